// Round 3
// baseline (366.167 us; speedup 1.0000x reference)
//
#include <hip/hip_runtime.h>

// Problem constants (fixed by the reference)
#define N_NODES 16384
#define N_EDGES 262144
#define E_TOT   (N_EDGES + N_NODES)   // edges + self loops = 278528
#define NEG_SLOPE 0.2f

typedef __attribute__((ext_vector_type(8))) short short8;
typedef __attribute__((ext_vector_type(4))) float floatx4;
typedef __attribute__((ext_vector_type(2))) float floatx2;

__device__ __forceinline__ ushort f2bf(float f) {
    unsigned u = __float_as_uint(f);
    u += 0x7fffu + ((u >> 16) & 1u);   // round-to-nearest-even
    return (ushort)(u >> 16);
}
__device__ __forceinline__ short8 pack8(floatx4 lo, floatx4 hi) {
    short8 r;
    r[0] = (short)f2bf(lo[0]); r[1] = (short)f2bf(lo[1]);
    r[2] = (short)f2bf(lo[2]); r[3] = (short)f2bf(lo[3]);
    r[4] = (short)f2bf(hi[0]); r[5] = (short)f2bf(hi[1]);
    r[6] = (short)f2bf(hi[2]); r[7] = (short)f2bf(hi[3]);
    return r;
}
__device__ __forceinline__ float leaky(float x) {
    return x > 0.f ? x : NEG_SLOPE * x;
}

// ---------------------------------------------------------------------------
// CSR build: histogram of dst, exclusive scan, scatter src indices
// ---------------------------------------------------------------------------
__global__ __launch_bounds__(256) void k_hist(const int* __restrict__ adj,
                                              int* __restrict__ counts) {
    int e = blockIdx.x * 256 + threadIdx.x;
    if (e < E_TOT) {
        int d = (e < N_EDGES) ? adj[N_EDGES + e] : (e - N_EDGES);
        atomicAdd(&counts[d], 1);
    }
}

__global__ __launch_bounds__(1024) void k_scan(const int* __restrict__ counts,
                                               int* __restrict__ offs,
                                               int* __restrict__ cursor) {
    __shared__ int part[1024];
    int t = threadIdx.x;
    int local[16];
    int sum = 0;
#pragma unroll
    for (int i = 0; i < 16; i++) {
        local[i] = sum;
        sum += counts[t * 16 + i];
    }
    part[t] = sum;
    __syncthreads();
    for (int d = 1; d < 1024; d <<= 1) {
        int v = (t >= d) ? part[t - d] : 0;
        __syncthreads();
        part[t] += v;
        __syncthreads();
    }
    int base = (t == 0) ? 0 : part[t - 1];
#pragma unroll
    for (int i = 0; i < 16; i++) {
        int o = base + local[i];
        offs[t * 16 + i] = o;
        cursor[t * 16 + i] = o;
    }
    if (t == 1023) offs[N_NODES] = part[1023];
}

__global__ __launch_bounds__(256) void k_scatter(const int* __restrict__ adj,
                                                 int* __restrict__ cursor,
                                                 int* __restrict__ esrc) {
    int e = blockIdx.x * 256 + threadIdx.x;
    if (e < E_TOT) {
        int s, d;
        if (e < N_EDGES) { s = adj[e]; d = adj[N_EDGES + e]; }
        else             { s = e - N_EDGES; d = s; }
        int pos = atomicAdd(&cursor[d], 1);
        esrc[pos] = s;
    }
}

// ---------------------------------------------------------------------------
// Weight transpose + f32->bf16: WT[n*K + k] = bf16(W[k*N + n])
// ---------------------------------------------------------------------------
__global__ __launch_bounds__(256) void k_transpose(const float* __restrict__ W,
                                                   ushort* __restrict__ WT,
                                                   int K, int N) {
    int idx = blockIdx.x * 256 + threadIdx.x;
    if (idx < K * N) {
        int k = idx / N, n = idx - k * N;
        WT[n * K + k] = f2bf(W[idx]);
    }
}

// ---------------------------------------------------------------------------
// MFMA GEMM: C[M,Nc] = act(A[M,K] @ B[K,Nc] + bias), fp32 in/out,
// bf16 MFMA inside (A converted during LDS staging; BT pre-converted bf16).
// Block 256 = 4 waves; tile 64x64, BK=64.
// mfma_f32_16x16x32_bf16 layouts (HW-verified per guide):
//   A frag: A[m=lane&15][k=(lane>>4)*8 + j]
//   B frag: B[k=(lane>>4)*8 + j][n=lane&15]  (read from BT rows)
//   C/D:    col=lane&15, row=(lane>>4)*4 + reg
// ---------------------------------------------------------------------------
#define BM 64
#define BN 64
#define BK 64
#define LDK (BK + 8)   // +8 bf16 pad -> only 2-way bank aliasing (free)

__global__ __launch_bounds__(256) void gemm_bt(const float* __restrict__ A,
                                               const ushort* __restrict__ BT,
                                               const float* __restrict__ bias,
                                               float* __restrict__ C,
                                               int M, int Nc, int K, int relu) {
    __shared__ ushort As[BM * LDK];
    __shared__ ushort Bs[BN * LDK];
    int tid  = threadIdx.x;
    int wave = tid >> 6, lane = tid & 63;
    int quad = lane >> 4, l16 = lane & 15;
    int bm = blockIdx.x * BM, bn = blockIdx.y * BN;

    floatx4 acc[4];
#pragma unroll
    for (int j = 0; j < 4; j++) acc[j] = (floatx4){0.f, 0.f, 0.f, 0.f};

    int srow = tid >> 3;         // 0..31
    int skc  = (tid & 7) * 8;    // 0..56

    for (int kb = 0; kb < K; kb += BK) {
        // A: fp32 -> bf16 during staging (rows srow, srow+32)
        const float* ga = A + (size_t)(bm + srow) * K + kb + skc;
        floatx4 a00 = *(const floatx4*)ga;
        floatx4 a01 = *(const floatx4*)(ga + 4);
        const float* ga1 = ga + (size_t)32 * K;
        floatx4 a10 = *(const floatx4*)ga1;
        floatx4 a11 = *(const floatx4*)(ga1 + 4);
        // B: already bf16 (BT rows = columns of B)
        const ushort* gb = BT + (size_t)(bn + srow) * K + kb + skc;
        short8 b0 = *(const short8*)gb;
        short8 b1 = *(const short8*)(gb + (size_t)32 * K);
        *(short8*)&As[srow * LDK + skc] = pack8(a00, a01);
        *(short8*)&As[(srow + 32) * LDK + skc] = pack8(a10, a11);
        *(short8*)&Bs[srow * LDK + skc] = b0;
        *(short8*)&Bs[(srow + 32) * LDK + skc] = b1;
        __syncthreads();

        int arow = wave * 16 + l16;
#pragma unroll
        for (int kk = 0; kk < BK; kk += 32) {
            short8 a = *(const short8*)&As[arow * LDK + kk + quad * 8];
#pragma unroll
            for (int j4 = 0; j4 < 4; j4++) {
                short8 b = *(const short8*)&Bs[(j4 * 16 + l16) * LDK + kk + quad * 8];
                acc[j4] = __builtin_amdgcn_mfma_f32_16x16x32_bf16(a, b, acc[j4], 0, 0, 0);
            }
        }
        __syncthreads();
    }

    int row = bm + wave * 16 + quad * 4;
#pragma unroll
    for (int j4 = 0; j4 < 4; j4++) {
        int col = bn + j4 * 16 + l16;
        float bv = bias ? bias[col] : 0.f;
#pragma unroll
        for (int i = 0; i < 4; i++) {
            float v = acc[j4][i] + bv;
            if (relu) v = fmaxf(v, 0.f);
            C[(size_t)(row + i) * Nc + col] = v;
        }
    }
}

// ---------------------------------------------------------------------------
// Attention logits (fp32): one wave per node.
// heads=2: lanes 0..31 -> head0 (c 0..255), lanes 32..63 -> head1.
// ---------------------------------------------------------------------------
__global__ __launch_bounds__(256) void k_dots(const float* __restrict__ h,
                                              const float* __restrict__ asrc,
                                              const float* __restrict__ adst,
                                              float* __restrict__ als,
                                              float* __restrict__ ald,
                                              int heads) {
    int wave = threadIdx.x >> 6, lane = threadIdx.x & 63;
    int n = blockIdx.x * 4 + wave;
    const float* hr = h + (size_t)n * 512;
    int c = lane * 8;
    floatx4 h0 = *(const floatx4*)(hr + c);
    floatx4 h1 = *(const floatx4*)(hr + c + 4);
    floatx4 s0 = *(const floatx4*)(asrc + c);
    floatx4 s1 = *(const floatx4*)(asrc + c + 4);
    floatx4 d0 = *(const floatx4*)(adst + c);
    floatx4 d1 = *(const floatx4*)(adst + c + 4);
    float ps = 0.f, pd = 0.f;
#pragma unroll
    for (int j = 0; j < 4; j++) {
        ps += h0[j] * s0[j] + h1[j] * s1[j];
        pd += h0[j] * d0[j] + h1[j] * d1[j];
    }
    int w = (heads == 2) ? 32 : 64;
    for (int m = 1; m < w; m <<= 1) {
        ps += __shfl_xor(ps, m, 64);
        pd += __shfl_xor(pd, m, 64);
    }
    if (heads == 2) {
        if (lane == 0)  { als[n * 2]     = ps; ald[n * 2]     = pd; }
        if (lane == 32) { als[n * 2 + 1] = ps; ald[n * 2 + 1] = pd; }
    } else {
        if (lane == 0)  { als[n] = ps; ald[n] = pd; }
    }
}

// ---------------------------------------------------------------------------
// Segment softmax + weighted aggregation per dst node (CSR), fp32.
// One block (256 thr) per node; thread t owns channels 2t, 2t+1 (same head).
// ---------------------------------------------------------------------------
__global__ __launch_bounds__(256) void k_agg(const float* __restrict__ h,
                                             const float* __restrict__ als,
                                             const float* __restrict__ ald,
                                             const int* __restrict__ offs,
                                             const int* __restrict__ esrc,
                                             const float* __restrict__ bias,
                                             float* __restrict__ out,
                                             int heads) {
    __shared__ float red0[256], red1[256];
    __shared__ float sA0[256], sA1[256];
    __shared__ int sSrc[256];

    int n = blockIdx.x, tid = threadIdx.x;
    int base = offs[n];
    int deg  = offs[n + 1] - base;
    float ald0 = ald[n * heads];
    float ald1 = (heads == 2) ? ald[n * heads + 1] : 0.f;

    // pass 1: per-head max
    float m0 = -1e30f, m1 = -1e30f;
    for (int i = tid; i < deg; i += 256) {
        int s = esrc[base + i];
        float e0 = leaky(als[s * heads] + ald0);
        m0 = fmaxf(m0, e0);
        if (heads == 2) {
            float e1 = leaky(als[s * 2 + 1] + ald1);
            m1 = fmaxf(m1, e1);
        }
    }
    red0[tid] = m0; red1[tid] = m1;
    __syncthreads();
    for (int st = 128; st > 0; st >>= 1) {
        if (tid < st) {
            red0[tid] = fmaxf(red0[tid], red0[tid + st]);
            red1[tid] = fmaxf(red1[tid], red1[tid + st]);
        }
        __syncthreads();
    }
    m0 = red0[0]; m1 = red1[0];
    __syncthreads();

    // pass 2: per-head sum of exp
    float s0 = 0.f, s1 = 0.f;
    for (int i = tid; i < deg; i += 256) {
        int s = esrc[base + i];
        float e0 = leaky(als[s * heads] + ald0);
        s0 += __expf(e0 - m0);
        if (heads == 2) {
            float e1 = leaky(als[s * 2 + 1] + ald1);
            s1 += __expf(e1 - m1);
        }
    }
    red0[tid] = s0; red1[tid] = s1;
    __syncthreads();
    for (int st = 128; st > 0; st >>= 1) {
        if (tid < st) {
            red0[tid] += red0[tid + st];
            red1[tid] += red1[tid + st];
        }
        __syncthreads();
    }
    float inv0 = 1.f / (red0[0] + 1e-16f);
    float inv1 = 1.f / (red1[0] + 1e-16f);
    __syncthreads();

    // pass 3: weighted aggregation, 2 channels per thread
    float acc0 = 0.f, acc1 = 0.f;
    int c0 = tid * 2;
    bool useH1 = (heads == 2) && (tid >= 128);
    for (int chunk = 0; chunk < deg; chunk += 256) {
        int i = chunk + tid;
        if (i < deg) {
            int s = esrc[base + i];
            sSrc[tid] = s;
            float e0 = leaky(als[s * heads] + ald0);
            sA0[tid] = __expf(e0 - m0) * inv0;
            if (heads == 2) {
                float e1 = leaky(als[s * 2 + 1] + ald1);
                sA1[tid] = __expf(e1 - m1) * inv1;
            }
        }
        __syncthreads();
        int cnt = min(256, deg - chunk);
        for (int j = 0; j < cnt; j++) {
            int s = sSrc[j];
            floatx2 pv = *(const floatx2*)(h + (size_t)s * 512 + c0);
            float al = useH1 ? sA1[j] : sA0[j];
            acc0 += al * pv[0];
            acc1 += al * pv[1];
        }
        __syncthreads();
    }

    floatx2 v;
    v[0] = fmaxf(acc0 + bias[c0], 0.f);
    v[1] = fmaxf(acc1 + bias[c0 + 1], 0.f);
    *(floatx2*)(out + (size_t)n * 512 + c0) = v;
}

// ---------------------------------------------------------------------------
// All float tensors are fp32 (reference uses jnp.float32); adj is int32.
// Workspace ~52 MiB. gat1 output parked in d_out (fp32 [N,512] = out_size;
// dead before the final k_agg overwrites it).
// ---------------------------------------------------------------------------
extern "C" void kernel_launch(void* const* d_in, const int* in_sizes, int n_in,
                              void* d_out, int out_size, void* d_ws, size_t ws_size,
                              hipStream_t stream) {
    const float* x   = (const float*)d_in[0];
    const int*   adj = (const int*)d_in[1];
    const float* Wfc = (const float*)d_in[2];
    const float* bfc = (const float*)d_in[3];
    const float* W1  = (const float*)d_in[4];
    const float* a1s = (const float*)d_in[5];
    const float* a1d = (const float*)d_in[6];
    const float* b1  = (const float*)d_in[7];
    const float* W2  = (const float*)d_in[8];
    const float* a2s = (const float*)d_in[9];
    const float* a2d = (const float*)d_in[10];
    const float* b2  = (const float*)d_in[11];
    float* out = (float*)d_out;

    char* ws = (char*)d_ws;
    size_t off = 0;
    auto alloc = [&](size_t bytes) -> void* {
        void* p = ws + off;
        off += (bytes + 255) & ~(size_t)255;
        return p;
    };
    float* h0    = (float*)alloc((size_t)N_NODES * 256 * 4);   // 16 MiB (fc out)
    float* hbuf  = (float*)alloc((size_t)N_NODES * 512 * 4);   // 32 MiB (h1 then h2)
    int* counts  = (int*)alloc(N_NODES * 4);
    int* offs    = (int*)alloc((N_NODES + 1) * 4);
    int* cursor  = (int*)alloc(N_NODES * 4);
    int* esrc    = (int*)alloc(E_TOT * 4);
    ushort* WfcT = (ushort*)alloc(256 * 256 * 2);
    ushort* W1T  = (ushort*)alloc(512 * 256 * 2);
    ushort* W2T  = (ushort*)alloc(512 * 512 * 2);
    float* als1  = (float*)alloc(N_NODES * 2 * 4);
    float* ald1  = (float*)alloc(N_NODES * 2 * 4);
    float* als2  = (float*)alloc(N_NODES * 4);
    float* ald2  = (float*)alloc(N_NODES * 4);
    float* g1    = out;   // gat1 output parked in d_out (32 MiB scratch)

    // CSR build
    hipMemsetAsync(counts, 0, N_NODES * 4, stream);
    k_hist<<<(E_TOT + 255) / 256, 256, 0, stream>>>(adj, counts);
    k_scan<<<1, 1024, 0, stream>>>(counts, offs, cursor);
    k_scatter<<<(E_TOT + 255) / 256, 256, 0, stream>>>(adj, cursor, esrc);

    // weight transposes (f32 -> bf16)
    k_transpose<<<(256 * 256 + 255) / 256, 256, 0, stream>>>(Wfc, WfcT, 256, 256);
    k_transpose<<<(256 * 512 + 255) / 256, 256, 0, stream>>>(W1, W1T, 256, 512);
    k_transpose<<<(512 * 512 + 255) / 256, 256, 0, stream>>>(W2, W2T, 512, 512);

    // h0 = relu(x @ Wfc + bfc)            [N,256]
    gemm_bt<<<dim3(N_NODES / BM, 256 / BN), 256, 0, stream>>>(x, WfcT, bfc, h0,
                                                              N_NODES, 256, 256, 1);
    // h1 = h0 @ W1                        [N,512]
    gemm_bt<<<dim3(N_NODES / BM, 512 / BN), 256, 0, stream>>>(h0, W1T, nullptr, hbuf,
                                                              N_NODES, 512, 256, 0);
    // gat1 attention + aggregation -> relu -> g1 (= d_out scratch)
    k_dots<<<N_NODES / 4, 256, 0, stream>>>(hbuf, a1s, a1d, als1, ald1, 2);
    k_agg<<<N_NODES, 256, 0, stream>>>(hbuf, als1, ald1, offs, esrc, b1, g1, 2);

    // h2 = g1 @ W2                        [N,512]  (hbuf reused; h1 dead)
    gemm_bt<<<dim3(N_NODES / BM, 512 / BN), 256, 0, stream>>>(g1, W2T, nullptr, hbuf,
                                                              N_NODES, 512, 512, 0);
    // gat2 attention + aggregation -> relu -> out (overwrites g1, which is dead)
    k_dots<<<N_NODES / 4, 256, 0, stream>>>(hbuf, a2s, a2d, als2, ald2, 1);
    k_agg<<<N_NODES, 256, 0, stream>>>(hbuf, als2, ald2, offs, esrc, b2, out, 1);
}

// Round 4
// 307.333 us; speedup vs baseline: 1.1914x; 1.1914x over previous
//
#include <hip/hip_runtime.h>

// Problem constants (fixed by the reference)
#define N_NODES 16384
#define N_EDGES 262144
#define E_TOT   (N_EDGES + N_NODES)   // edges + self loops = 278528
#define NEG_SLOPE 0.2f

typedef __attribute__((ext_vector_type(8))) short short8;
typedef __attribute__((ext_vector_type(4))) float floatx4;
typedef __attribute__((ext_vector_type(2))) float floatx2;

__device__ __forceinline__ float bf2f(ushort u) {
    return __uint_as_float(((unsigned)u) << 16);
}
__device__ __forceinline__ ushort f2bf(float f) {
    unsigned u = __float_as_uint(f);
    u += 0x7fffu + ((u >> 16) & 1u);   // round-to-nearest-even
    return (ushort)(u >> 16);
}
__device__ __forceinline__ float leaky(float x) {
    return x > 0.f ? x : NEG_SLOPE * x;
}

// ---------------------------------------------------------------------------
// f32 -> bf16 cast (vectorized, 8 elems/thread)
// ---------------------------------------------------------------------------
__global__ __launch_bounds__(256) void k_cast(const float* __restrict__ in,
                                              ushort* __restrict__ out, int n8) {
    int i = blockIdx.x * 256 + threadIdx.x;
    if (i < n8) {
        floatx4 v0 = *(const floatx4*)(in + i * 8);
        floatx4 v1 = *(const floatx4*)(in + i * 8 + 4);
        short8 r;
        r[0] = (short)f2bf(v0[0]); r[1] = (short)f2bf(v0[1]);
        r[2] = (short)f2bf(v0[2]); r[3] = (short)f2bf(v0[3]);
        r[4] = (short)f2bf(v1[0]); r[5] = (short)f2bf(v1[1]);
        r[6] = (short)f2bf(v1[2]); r[7] = (short)f2bf(v1[3]);
        *(short8*)(out + i * 8) = r;
    }
}

// ---------------------------------------------------------------------------
// CSR build: histogram of dst, exclusive scan, scatter src indices
// ---------------------------------------------------------------------------
__global__ __launch_bounds__(256) void k_hist(const int* __restrict__ adj,
                                              int* __restrict__ counts) {
    int e = blockIdx.x * 256 + threadIdx.x;
    if (e < E_TOT) {
        int d = (e < N_EDGES) ? adj[N_EDGES + e] : (e - N_EDGES);
        atomicAdd(&counts[d], 1);
    }
}

__global__ __launch_bounds__(1024) void k_scan(const int* __restrict__ counts,
                                               int* __restrict__ offs,
                                               int* __restrict__ cursor) {
    __shared__ int part[1024];
    int t = threadIdx.x;
    int local[16];
    int sum = 0;
#pragma unroll
    for (int i = 0; i < 16; i++) {
        local[i] = sum;
        sum += counts[t * 16 + i];
    }
    part[t] = sum;
    __syncthreads();
    for (int d = 1; d < 1024; d <<= 1) {
        int v = (t >= d) ? part[t - d] : 0;
        __syncthreads();
        part[t] += v;
        __syncthreads();
    }
    int base = (t == 0) ? 0 : part[t - 1];
#pragma unroll
    for (int i = 0; i < 16; i++) {
        int o = base + local[i];
        offs[t * 16 + i] = o;
        cursor[t * 16 + i] = o;
    }
    if (t == 1023) offs[N_NODES] = part[1023];
}

__global__ __launch_bounds__(256) void k_scatter(const int* __restrict__ adj,
                                                 int* __restrict__ cursor,
                                                 int* __restrict__ esrc) {
    int e = blockIdx.x * 256 + threadIdx.x;
    if (e < E_TOT) {
        int s, d;
        if (e < N_EDGES) { s = adj[e]; d = adj[N_EDGES + e]; }
        else             { s = e - N_EDGES; d = s; }
        int pos = atomicAdd(&cursor[d], 1);
        esrc[pos] = s;
    }
}

// ---------------------------------------------------------------------------
// Weight transpose + f32->bf16: WT[n*K + k] = bf16(W[k*N + n])
// ---------------------------------------------------------------------------
__global__ __launch_bounds__(256) void k_transpose(const float* __restrict__ W,
                                                   ushort* __restrict__ WT,
                                                   int K, int N) {
    int idx = blockIdx.x * 256 + threadIdx.x;
    if (idx < K * N) {
        int k = idx / N, n = idx - k * N;
        WT[n * K + k] = f2bf(W[idx]);
    }
}

// ---------------------------------------------------------------------------
// bf16 MFMA GEMM: C[M,Nc] = act(A[M,K] @ B[K,Nc] + bias)  (bf16 in, bf16 out,
// fp32 bias, fp32 accumulate). Block 256 = 4 waves; tile 64x64, BK=64.
// mfma_f32_16x16x32_bf16 layouts (HW-verified per guide):
//   A frag: A[m=lane&15][k=(lane>>4)*8 + j]
//   B frag: B[k=(lane>>4)*8 + j][n=lane&15]  (read from BT rows)
//   C/D:    col=lane&15, row=(lane>>4)*4 + reg
// ---------------------------------------------------------------------------
#define BM 64
#define BN 64
#define BK 64
#define LDK (BK + 8)   // +8 bf16 pad -> only 2-way bank aliasing (free)

__global__ __launch_bounds__(256) void gemm_bt(const ushort* __restrict__ A,
                                               const ushort* __restrict__ BT,
                                               const float* __restrict__ bias,
                                               ushort* __restrict__ C,
                                               int M, int Nc, int K, int relu) {
    __shared__ ushort As[BM * LDK];
    __shared__ ushort Bs[BN * LDK];
    int tid  = threadIdx.x;
    int wave = tid >> 6, lane = tid & 63;
    int quad = lane >> 4, l16 = lane & 15;
    int bm = blockIdx.x * BM, bn = blockIdx.y * BN;

    floatx4 acc[4];
#pragma unroll
    for (int j = 0; j < 4; j++) acc[j] = (floatx4){0.f, 0.f, 0.f, 0.f};

    int srow = tid >> 3;         // 0..31
    int skc  = (tid & 7) * 8;    // 0..56

    for (int kb = 0; kb < K; kb += BK) {
        const ushort* ga = A + (size_t)(bm + srow) * K + kb + skc;
        short8 a0 = *(const short8*)ga;
        short8 a1 = *(const short8*)(ga + (size_t)32 * K);
        const ushort* gb = BT + (size_t)(bn + srow) * K + kb + skc;
        short8 b0 = *(const short8*)gb;
        short8 b1 = *(const short8*)(gb + (size_t)32 * K);
        *(short8*)&As[srow * LDK + skc] = a0;
        *(short8*)&As[(srow + 32) * LDK + skc] = a1;
        *(short8*)&Bs[srow * LDK + skc] = b0;
        *(short8*)&Bs[(srow + 32) * LDK + skc] = b1;
        __syncthreads();

        int arow = wave * 16 + l16;
#pragma unroll
        for (int kk = 0; kk < BK; kk += 32) {
            short8 a = *(const short8*)&As[arow * LDK + kk + quad * 8];
#pragma unroll
            for (int j4 = 0; j4 < 4; j4++) {
                short8 b = *(const short8*)&Bs[(j4 * 16 + l16) * LDK + kk + quad * 8];
                acc[j4] = __builtin_amdgcn_mfma_f32_16x16x32_bf16(a, b, acc[j4], 0, 0, 0);
            }
        }
        __syncthreads();
    }

    int row = bm + wave * 16 + quad * 4;
#pragma unroll
    for (int j4 = 0; j4 < 4; j4++) {
        int col = bn + j4 * 16 + l16;
        float bv = bias ? bias[col] : 0.f;
#pragma unroll
        for (int i = 0; i < 4; i++) {
            float v = acc[j4][i] + bv;
            if (relu) v = fmaxf(v, 0.f);
            C[(size_t)(row + i) * Nc + col] = f2bf(v);
        }
    }
}

// ---------------------------------------------------------------------------
// Attention logits: h bf16, a-vectors fp32. One wave per node.
// heads=2: lanes 0..31 -> head0 (c 0..255), lanes 32..63 -> head1.
// ---------------------------------------------------------------------------
__global__ __launch_bounds__(256) void k_dots(const ushort* __restrict__ h,
                                              const float* __restrict__ asrc,
                                              const float* __restrict__ adst,
                                              float* __restrict__ als,
                                              float* __restrict__ ald,
                                              int heads) {
    int wave = threadIdx.x >> 6, lane = threadIdx.x & 63;
    int n = blockIdx.x * 4 + wave;
    const ushort* hr = h + (size_t)n * 512;
    int c = lane * 8;
    short8 hv = *(const short8*)(hr + c);
    floatx4 s0 = *(const floatx4*)(asrc + c);
    floatx4 s1 = *(const floatx4*)(asrc + c + 4);
    floatx4 d0 = *(const floatx4*)(adst + c);
    floatx4 d1 = *(const floatx4*)(adst + c + 4);
    float ps = 0.f, pd = 0.f;
#pragma unroll
    for (int j = 0; j < 4; j++) {
        float hf0 = bf2f((ushort)hv[j]);
        float hf1 = bf2f((ushort)hv[j + 4]);
        ps += hf0 * s0[j] + hf1 * s1[j];
        pd += hf0 * d0[j] + hf1 * d1[j];
    }
    int w = (heads == 2) ? 32 : 64;
    for (int m = 1; m < w; m <<= 1) {
        ps += __shfl_xor(ps, m, 64);
        pd += __shfl_xor(pd, m, 64);
    }
    if (heads == 2) {
        if (lane == 0)  { als[n * 2]     = ps; ald[n * 2]     = pd; }
        if (lane == 32) { als[n * 2 + 1] = ps; ald[n * 2 + 1] = pd; }
    } else {
        if (lane == 0)  { als[n] = ps; ald[n] = pd; }
    }
}

// ---------------------------------------------------------------------------
// Segment softmax + weighted aggregation per dst node (CSR).
// h gathered as bf16; fp32 accumulate. One block (256 thr) per node;
// thread t owns channels 2t, 2t+1 (same head). Output bf16 (outb) or fp32
// (outf) — exactly one of the two pointers is non-null.
// ---------------------------------------------------------------------------
__global__ __launch_bounds__(256) void k_agg(const ushort* __restrict__ h,
                                             const float* __restrict__ als,
                                             const float* __restrict__ ald,
                                             const int* __restrict__ offs,
                                             const int* __restrict__ esrc,
                                             const float* __restrict__ bias,
                                             ushort* __restrict__ outb,
                                             float* __restrict__ outf,
                                             int heads) {
    __shared__ float red0[256], red1[256];
    __shared__ float sA0[256], sA1[256];
    __shared__ int sSrc[256];

    int n = blockIdx.x, tid = threadIdx.x;
    int base = offs[n];
    int deg  = offs[n + 1] - base;
    float ald0 = ald[n * heads];
    float ald1 = (heads == 2) ? ald[n * heads + 1] : 0.f;

    // pass 1: per-head max
    float m0 = -1e30f, m1 = -1e30f;
    for (int i = tid; i < deg; i += 256) {
        int s = esrc[base + i];
        float e0 = leaky(als[s * heads] + ald0);
        m0 = fmaxf(m0, e0);
        if (heads == 2) {
            float e1 = leaky(als[s * 2 + 1] + ald1);
            m1 = fmaxf(m1, e1);
        }
    }
    red0[tid] = m0; red1[tid] = m1;
    __syncthreads();
    for (int st = 128; st > 0; st >>= 1) {
        if (tid < st) {
            red0[tid] = fmaxf(red0[tid], red0[tid + st]);
            red1[tid] = fmaxf(red1[tid], red1[tid + st]);
        }
        __syncthreads();
    }
    m0 = red0[0]; m1 = red1[0];
    __syncthreads();

    // pass 2: per-head sum of exp
    float s0 = 0.f, s1 = 0.f;
    for (int i = tid; i < deg; i += 256) {
        int s = esrc[base + i];
        float e0 = leaky(als[s * heads] + ald0);
        s0 += __expf(e0 - m0);
        if (heads == 2) {
            float e1 = leaky(als[s * 2 + 1] + ald1);
            s1 += __expf(e1 - m1);
        }
    }
    red0[tid] = s0; red1[tid] = s1;
    __syncthreads();
    for (int st = 128; st > 0; st >>= 1) {
        if (tid < st) {
            red0[tid] += red0[tid + st];
            red1[tid] += red1[tid + st];
        }
        __syncthreads();
    }
    float inv0 = 1.f / (red0[0] + 1e-16f);
    float inv1 = 1.f / (red1[0] + 1e-16f);
    __syncthreads();

    // pass 3: weighted aggregation; bf16 gather (4B per thread per edge:
    // 256 thr x 4B = full 1KB bf16 row, coalesced)
    float acc0 = 0.f, acc1 = 0.f;
    int c0 = tid * 2;
    bool useH1 = (heads == 2) && (tid >= 128);
    for (int chunk = 0; chunk < deg; chunk += 256) {
        int i = chunk + tid;
        if (i < deg) {
            int s = esrc[base + i];
            sSrc[tid] = s;
            float e0 = leaky(als[s * heads] + ald0);
            sA0[tid] = __expf(e0 - m0) * inv0;
            if (heads == 2) {
                float e1 = leaky(als[s * 2 + 1] + ald1);
                sA1[tid] = __expf(e1 - m1) * inv1;
            }
        }
        __syncthreads();
        int cnt = min(256, deg - chunk);
        for (int j = 0; j < cnt; j++) {
            int s = sSrc[j];
            unsigned pv = *(const unsigned*)(h + (size_t)s * 512 + c0);
            float al = useH1 ? sA1[j] : sA0[j];
            acc0 += al * bf2f((ushort)(pv & 0xffffu));
            acc1 += al * bf2f((ushort)(pv >> 16));
        }
        __syncthreads();
    }

    float v0 = fmaxf(acc0 + bias[c0], 0.f);
    float v1 = fmaxf(acc1 + bias[c0 + 1], 0.f);
    if (outf) {
        floatx2 v; v[0] = v0; v[1] = v1;
        *(floatx2*)(outf + (size_t)n * 512 + c0) = v;
    } else {
        unsigned packed = (unsigned)f2bf(v0) | ((unsigned)f2bf(v1) << 16);
        *(unsigned*)(outb + (size_t)n * 512 + c0) = packed;
    }
}

// ---------------------------------------------------------------------------
// R4: all intermediates bf16 (halves gather/dot/GEMM-staging traffic);
// fp32 accumulate everywhere; final output fp32. Workspace ~52 MiB.
// ---------------------------------------------------------------------------
extern "C" void kernel_launch(void* const* d_in, const int* in_sizes, int n_in,
                              void* d_out, int out_size, void* d_ws, size_t ws_size,
                              hipStream_t stream) {
    const float* x   = (const float*)d_in[0];
    const int*   adj = (const int*)d_in[1];
    const float* Wfc = (const float*)d_in[2];
    const float* bfc = (const float*)d_in[3];
    const float* W1  = (const float*)d_in[4];
    const float* a1s = (const float*)d_in[5];
    const float* a1d = (const float*)d_in[6];
    const float* b1  = (const float*)d_in[7];
    const float* W2  = (const float*)d_in[8];
    const float* a2s = (const float*)d_in[9];
    const float* a2d = (const float*)d_in[10];
    const float* b2  = (const float*)d_in[11];
    float* out = (float*)d_out;

    char* ws = (char*)d_ws;
    size_t off = 0;
    auto alloc = [&](size_t bytes) -> void* {
        void* p = ws + off;
        off += (bytes + 255) & ~(size_t)255;
        return p;
    };
    ushort* xb   = (ushort*)alloc((size_t)N_NODES * 256 * 2);  //  8 MiB
    ushort* h0b  = (ushort*)alloc((size_t)N_NODES * 256 * 2);  //  8 MiB (fc out)
    ushort* h1b  = (ushort*)alloc((size_t)N_NODES * 512 * 2);  // 16 MiB (h1, reused as h2)
    ushort* g1b  = (ushort*)alloc((size_t)N_NODES * 512 * 2);  // 16 MiB (gat1 out)
    int* counts  = (int*)alloc(N_NODES * 4);
    int* offs    = (int*)alloc((N_NODES + 1) * 4);
    int* cursor  = (int*)alloc(N_NODES * 4);
    int* esrc    = (int*)alloc(E_TOT * 4);
    ushort* WfcT = (ushort*)alloc(256 * 256 * 2);
    ushort* W1T  = (ushort*)alloc(512 * 256 * 2);
    ushort* W2T  = (ushort*)alloc(512 * 512 * 2);
    float* als1  = (float*)alloc(N_NODES * 2 * 4);
    float* ald1  = (float*)alloc(N_NODES * 2 * 4);
    float* als2  = (float*)alloc(N_NODES * 4);
    float* ald2  = (float*)alloc(N_NODES * 4);

    // cast x to bf16
    k_cast<<<(N_NODES * 256 / 8 + 255) / 256, 256, 0, stream>>>(x, xb, N_NODES * 256 / 8);

    // CSR build
    hipMemsetAsync(counts, 0, N_NODES * 4, stream);
    k_hist<<<(E_TOT + 255) / 256, 256, 0, stream>>>(adj, counts);
    k_scan<<<1, 1024, 0, stream>>>(counts, offs, cursor);
    k_scatter<<<(E_TOT + 255) / 256, 256, 0, stream>>>(adj, cursor, esrc);

    // weight transposes (f32 -> bf16)
    k_transpose<<<(256 * 256 + 255) / 256, 256, 0, stream>>>(Wfc, WfcT, 256, 256);
    k_transpose<<<(256 * 512 + 255) / 256, 256, 0, stream>>>(W1, W1T, 256, 512);
    k_transpose<<<(512 * 512 + 255) / 256, 256, 0, stream>>>(W2, W2T, 512, 512);

    // h0 = relu(x @ Wfc + bfc)            [N,256] bf16
    gemm_bt<<<dim3(N_NODES / BM, 256 / BN), 256, 0, stream>>>(xb, WfcT, bfc, h0b,
                                                              N_NODES, 256, 256, 1);
    // h1 = h0 @ W1                        [N,512] bf16
    gemm_bt<<<dim3(N_NODES / BM, 512 / BN), 256, 0, stream>>>(h0b, W1T, nullptr, h1b,
                                                              N_NODES, 512, 256, 0);
    // gat1 attention + aggregation -> relu -> g1b (bf16)
    k_dots<<<N_NODES / 4, 256, 0, stream>>>(h1b, a1s, a1d, als1, ald1, 2);
    k_agg<<<N_NODES, 256, 0, stream>>>(h1b, als1, ald1, offs, esrc, b1,
                                       g1b, nullptr, 2);

    // h2 = g1 @ W2                        [N,512] bf16 (h1b reused; h1 dead)
    gemm_bt<<<dim3(N_NODES / BM, 512 / BN), 256, 0, stream>>>(g1b, W2T, nullptr, h1b,
                                                              N_NODES, 512, 512, 0);
    // gat2 attention + aggregation -> relu -> out (fp32)
    k_dots<<<N_NODES / 4, 256, 0, stream>>>(h1b, a2s, a2d, als2, ald2, 1);
    k_agg<<<N_NODES, 256, 0, stream>>>(h1b, als2, ald2, offs, esrc, b2,
                                       nullptr, out, 1);
}

// Round 5
// 269.189 us; speedup vs baseline: 1.3603x; 1.1417x over previous
//
#include <hip/hip_runtime.h>

// Problem constants (fixed by the reference)
#define N_NODES 16384
#define N_EDGES 262144
#define E_TOT   (N_EDGES + N_NODES)   // edges + self loops = 278528
#define NEG_SLOPE 0.2f

typedef __attribute__((ext_vector_type(8))) short short8;
typedef __attribute__((ext_vector_type(4))) float floatx4;
typedef __attribute__((ext_vector_type(2))) float floatx2;
typedef __attribute__((ext_vector_type(4))) int intx4;

__device__ __forceinline__ float bf2f(ushort u) {
    return __uint_as_float(((unsigned)u) << 16);
}
__device__ __forceinline__ ushort f2bf(float f) {
    unsigned u = __float_as_uint(f);
    u += 0x7fffu + ((u >> 16) & 1u);   // round-to-nearest-even
    return (ushort)(u >> 16);
}
__device__ __forceinline__ float leaky(float x) {
    return x > 0.f ? x : NEG_SLOPE * x;
}

// ---------------------------------------------------------------------------
// Fused prep: x f32->bf16 cast, 3 weight transposes (+bf16), counts zeroing.
// Segments over a flat thread index (saves 4 serialized graph nodes).
//   [0, 524288)            : cast x, 8 elems/thread (N*256 = 4194304 elems)
//   [524288, +65536)       : transpose Wfc (K=256,N=256)
//   [+, +131072)           : transpose W1  (K=256,N=512)
//   [+, +262144)           : transpose W2  (K=512,N=512)
//   [+, +4096)             : zero counts (int4/thread)
// total threads = 987136 = 3856 * 256
// ---------------------------------------------------------------------------
#define PREP_CAST   524288
#define PREP_T0     (PREP_CAST)
#define PREP_T1     (PREP_T0 + 65536)
#define PREP_T2     (PREP_T1 + 131072)
#define PREP_Z      (PREP_T2 + 262144)
#define PREP_TOT    (PREP_Z + 4096)

__global__ __launch_bounds__(256) void k_prep(const float* __restrict__ x,
                                              ushort* __restrict__ xb,
                                              const float* __restrict__ Wfc,
                                              ushort* __restrict__ WfcT,
                                              const float* __restrict__ W1,
                                              ushort* __restrict__ W1T,
                                              const float* __restrict__ W2,
                                              ushort* __restrict__ W2T,
                                              int* __restrict__ counts) {
    int idx = blockIdx.x * 256 + threadIdx.x;
    if (idx < PREP_CAST) {
        floatx4 v0 = *(const floatx4*)(x + (size_t)idx * 8);
        floatx4 v1 = *(const floatx4*)(x + (size_t)idx * 8 + 4);
        short8 r;
        r[0] = (short)f2bf(v0[0]); r[1] = (short)f2bf(v0[1]);
        r[2] = (short)f2bf(v0[2]); r[3] = (short)f2bf(v0[3]);
        r[4] = (short)f2bf(v1[0]); r[5] = (short)f2bf(v1[1]);
        r[6] = (short)f2bf(v1[2]); r[7] = (short)f2bf(v1[3]);
        *(short8*)(xb + (size_t)idx * 8) = r;
    } else if (idx < PREP_T1) {
        int t = idx - PREP_T0;                 // K=256, N=256
        int k = t >> 8, n = t & 255;
        WfcT[n * 256 + k] = f2bf(Wfc[t]);
    } else if (idx < PREP_T2) {
        int t = idx - PREP_T1;                 // K=256, N=512
        int k = t >> 9, n = t & 511;
        W1T[n * 256 + k] = f2bf(W1[t]);
    } else if (idx < PREP_Z) {
        int t = idx - PREP_T2;                 // K=512, N=512
        int k = t >> 9, n = t & 511;
        W2T[n * 512 + k] = f2bf(W2[t]);
    } else if (idx < PREP_TOT) {
        int t = idx - PREP_Z;
        *(intx4*)(counts + t * 4) = (intx4){0, 0, 0, 0};
    }
}

// ---------------------------------------------------------------------------
// CSR build: histogram of dst, exclusive scan, scatter src indices
// ---------------------------------------------------------------------------
__global__ __launch_bounds__(256) void k_hist(const int* __restrict__ adj,
                                              int* __restrict__ counts) {
    int e = blockIdx.x * 256 + threadIdx.x;
    if (e < E_TOT) {
        int d = (e < N_EDGES) ? adj[N_EDGES + e] : (e - N_EDGES);
        atomicAdd(&counts[d], 1);
    }
}

__global__ __launch_bounds__(1024) void k_scan(const int* __restrict__ counts,
                                               int* __restrict__ offs,
                                               int* __restrict__ cursor) {
    __shared__ int part[1024];
    int t = threadIdx.x;
    int local[16];
    int sum = 0;
#pragma unroll
    for (int i = 0; i < 16; i++) {
        local[i] = sum;
        sum += counts[t * 16 + i];
    }
    part[t] = sum;
    __syncthreads();
    for (int d = 1; d < 1024; d <<= 1) {
        int v = (t >= d) ? part[t - d] : 0;
        __syncthreads();
        part[t] += v;
        __syncthreads();
    }
    int base = (t == 0) ? 0 : part[t - 1];
#pragma unroll
    for (int i = 0; i < 16; i++) {
        int o = base + local[i];
        offs[t * 16 + i] = o;
        cursor[t * 16 + i] = o;
    }
    if (t == 1023) offs[N_NODES] = part[1023];
}

__global__ __launch_bounds__(256) void k_scatter(const int* __restrict__ adj,
                                                 int* __restrict__ cursor,
                                                 int* __restrict__ esrc) {
    int e = blockIdx.x * 256 + threadIdx.x;
    if (e < E_TOT) {
        int s, d;
        if (e < N_EDGES) { s = adj[e]; d = adj[N_EDGES + e]; }
        else             { s = e - N_EDGES; d = s; }
        int pos = atomicAdd(&cursor[d], 1);
        esrc[pos] = s;
    }
}

// ---------------------------------------------------------------------------
// bf16 MFMA GEMM: C[M,Nc] = act(A[M,K] @ B[K,Nc] + bias)  (bf16 in/out,
// fp32 bias + accumulate). Block 256 = 4 waves; tile 64x64, BK=64.
// mfma_f32_16x16x32_bf16 layouts (HW-verified per guide):
//   A frag: A[m=lane&15][k=(lane>>4)*8 + j]
//   B frag: B[k=(lane>>4)*8 + j][n=lane&15]  (read from BT rows)
//   C/D:    col=lane&15, row=(lane>>4)*4 + reg
// ---------------------------------------------------------------------------
#define BM 64
#define BN 64
#define BK 64
#define LDK (BK + 8)   // +8 bf16 pad -> only 2-way bank aliasing (free)

__global__ __launch_bounds__(256) void gemm_bt(const ushort* __restrict__ A,
                                               const ushort* __restrict__ BT,
                                               const float* __restrict__ bias,
                                               ushort* __restrict__ C,
                                               int M, int Nc, int K, int relu) {
    __shared__ ushort As[BM * LDK];
    __shared__ ushort Bs[BN * LDK];
    int tid  = threadIdx.x;
    int wave = tid >> 6, lane = tid & 63;
    int quad = lane >> 4, l16 = lane & 15;
    int bm = blockIdx.x * BM, bn = blockIdx.y * BN;

    floatx4 acc[4];
#pragma unroll
    for (int j = 0; j < 4; j++) acc[j] = (floatx4){0.f, 0.f, 0.f, 0.f};

    int srow = tid >> 3;         // 0..31
    int skc  = (tid & 7) * 8;    // 0..56

    for (int kb = 0; kb < K; kb += BK) {
        const ushort* ga = A + (size_t)(bm + srow) * K + kb + skc;
        short8 a0 = *(const short8*)ga;
        short8 a1 = *(const short8*)(ga + (size_t)32 * K);
        const ushort* gb = BT + (size_t)(bn + srow) * K + kb + skc;
        short8 b0 = *(const short8*)gb;
        short8 b1 = *(const short8*)(gb + (size_t)32 * K);
        *(short8*)&As[srow * LDK + skc] = a0;
        *(short8*)&As[(srow + 32) * LDK + skc] = a1;
        *(short8*)&Bs[srow * LDK + skc] = b0;
        *(short8*)&Bs[(srow + 32) * LDK + skc] = b1;
        __syncthreads();

        int arow = wave * 16 + l16;
#pragma unroll
        for (int kk = 0; kk < BK; kk += 32) {
            short8 a = *(const short8*)&As[arow * LDK + kk + quad * 8];
#pragma unroll
            for (int j4 = 0; j4 < 4; j4++) {
                short8 b = *(const short8*)&Bs[(j4 * 16 + l16) * LDK + kk + quad * 8];
                acc[j4] = __builtin_amdgcn_mfma_f32_16x16x32_bf16(a, b, acc[j4], 0, 0, 0);
            }
        }
        __syncthreads();
    }

    int row = bm + wave * 16 + quad * 4;
#pragma unroll
    for (int j4 = 0; j4 < 4; j4++) {
        int col = bn + j4 * 16 + l16;
        float bv = bias ? bias[col] : 0.f;
#pragma unroll
        for (int i = 0; i < 4; i++) {
            float v = acc[j4][i] + bv;
            if (relu) v = fmaxf(v, 0.f);
            C[(size_t)(row + i) * Nc + col] = f2bf(v);
        }
    }
}

// ---------------------------------------------------------------------------
// Attention logits: h bf16, a-vectors fp32. One wave per node.
// heads=2: lanes 0..31 -> head0 (c 0..255), lanes 32..63 -> head1.
// ---------------------------------------------------------------------------
__global__ __launch_bounds__(256) void k_dots(const ushort* __restrict__ h,
                                              const float* __restrict__ asrc,
                                              const float* __restrict__ adst,
                                              float* __restrict__ als,
                                              float* __restrict__ ald,
                                              int heads) {
    int wave = threadIdx.x >> 6, lane = threadIdx.x & 63;
    int n = blockIdx.x * 4 + wave;
    const ushort* hr = h + (size_t)n * 512;
    int c = lane * 8;
    short8 hv = *(const short8*)(hr + c);
    floatx4 s0 = *(const floatx4*)(asrc + c);
    floatx4 s1 = *(const floatx4*)(asrc + c + 4);
    floatx4 d0 = *(const floatx4*)(adst + c);
    floatx4 d1 = *(const floatx4*)(adst + c + 4);
    float ps = 0.f, pd = 0.f;
#pragma unroll
    for (int j = 0; j < 4; j++) {
        float hf0 = bf2f((ushort)hv[j]);
        float hf1 = bf2f((ushort)hv[j + 4]);
        ps += hf0 * s0[j] + hf1 * s1[j];
        pd += hf0 * d0[j] + hf1 * d1[j];
    }
    int w = (heads == 2) ? 32 : 64;
    for (int m = 1; m < w; m <<= 1) {
        ps += __shfl_xor(ps, m, 64);
        pd += __shfl_xor(pd, m, 64);
    }
    if (heads == 2) {
        if (lane == 0)  { als[n * 2]     = ps; ald[n * 2]     = pd; }
        if (lane == 32) { als[n * 2 + 1] = ps; ald[n * 2 + 1] = pd; }
    } else {
        if (lane == 0)  { als[n] = ps; ald[n] = pd; }
    }
}

// ---------------------------------------------------------------------------
// Segment softmax + weighted aggregation, ONE WAVE PER NODE, zero barriers.
// Softmax state via __shfl_xor reductions; inner gather is 16B/lane
// (bf16x8 = 8 channels/lane). src index and alpha broadcast from the
// owning lane's registers via __shfl — no LDS, no syncthreads.
// heads=2: lanes 0..31 head0 (c=lane*8), lanes 32..63 head1 (c=256+(lane&31)*8).
// ---------------------------------------------------------------------------
__global__ __launch_bounds__(256) void k_agg(const ushort* __restrict__ h,
                                             const float* __restrict__ als,
                                             const float* __restrict__ ald,
                                             const int* __restrict__ offs,
                                             const int* __restrict__ esrc,
                                             const float* __restrict__ bias,
                                             ushort* __restrict__ outb,
                                             float* __restrict__ outf,
                                             int heads) {
    int wave = threadIdx.x >> 6, lane = threadIdx.x & 63;
    int n = blockIdx.x * 4 + wave;
    int base = offs[n];
    int deg  = offs[n + 1] - base;

    int myhead = (heads == 2) ? (lane >> 5) : 0;
    int c = (heads == 2) ? (myhead * 256 + (lane & 31) * 8) : lane * 8;

    float aldh0 = ald[n * heads];
    float aldh1 = (heads == 2) ? ald[n * heads + 1] : 0.f;

    // pass 1: per-head max (all lanes compute both heads; shuffle-reduce)
    float m0 = -1e30f, m1 = -1e30f;
    for (int cb = 0; cb < deg; cb += 64) {
        int i = cb + lane;
        if (i < deg) {
            int s = esrc[base + i];
            m0 = fmaxf(m0, leaky(als[s * heads] + aldh0));
            if (heads == 2) m1 = fmaxf(m1, leaky(als[s * 2 + 1] + aldh1));
        }
    }
#pragma unroll
    for (int msk = 1; msk < 64; msk <<= 1) {
        m0 = fmaxf(m0, __shfl_xor(m0, msk, 64));
        m1 = fmaxf(m1, __shfl_xor(m1, msk, 64));
    }

    // pass 2: per-head denom
    float s0 = 0.f, s1 = 0.f;
    for (int cb = 0; cb < deg; cb += 64) {
        int i = cb + lane;
        if (i < deg) {
            int s = esrc[base + i];
            s0 += __expf(leaky(als[s * heads] + aldh0) - m0);
            if (heads == 2) s1 += __expf(leaky(als[s * 2 + 1] + aldh1) - m1);
        }
    }
#pragma unroll
    for (int msk = 1; msk < 64; msk <<= 1) {
        s0 += __shfl_xor(s0, msk, 64);
        s1 += __shfl_xor(s1, msk, 64);
    }
    float inv0 = 1.f / (s0 + 1e-16f);
    float inv1 = 1.f / (s1 + 1e-16f);

    // pass 3: weighted gather-accumulate, 8 channels (16B) per lane per edge
    float acc[8];
#pragma unroll
    for (int q = 0; q < 8; q++) acc[q] = 0.f;
    const ushort* hc = h + c;

    for (int cb = 0; cb < deg; cb += 64) {
        int i = cb + lane;
        int sv = 0;
        float p0 = 0.f, p1 = 0.f;
        if (i < deg) {
            sv = esrc[base + i];
            p0 = __expf(leaky(als[sv * heads] + aldh0) - m0) * inv0;
            if (heads == 2) p1 = __expf(leaky(als[sv * 2 + 1] + aldh1) - m1) * inv1;
        }
        int cnt = min(64, deg - cb);
        for (int j = 0; j < cnt; j++) {
            int s   = __shfl(sv, j, 64);
            float a0 = __shfl(p0, j, 64);
            float a1 = __shfl(p1, j, 64);
            float al = myhead ? a1 : a0;
            short8 hv = *(const short8*)(hc + (size_t)s * 512);
#pragma unroll
            for (int q = 0; q < 8; q++) acc[q] += al * bf2f((ushort)hv[q]);
        }
    }

    // epilogue: bias + relu + store
    float v[8];
#pragma unroll
    for (int q = 0; q < 8; q++) v[q] = fmaxf(acc[q] + bias[c + q], 0.f);
    if (outf) {
        float* op = outf + (size_t)n * 512 + c;
        *(floatx4*)op       = (floatx4){v[0], v[1], v[2], v[3]};
        *(floatx4*)(op + 4) = (floatx4){v[4], v[5], v[6], v[7]};
    } else {
        short8 r;
#pragma unroll
        for (int q = 0; q < 8; q++) r[q] = (short)f2bf(v[q]);
        *(short8*)(outb + (size_t)n * 512 + c) = r;
    }
}

// ---------------------------------------------------------------------------
// R5: wave-per-node barrier-free k_agg (16B gathers, shfl softmax);
// prep kernels fused into one dispatch. Workspace ~52 MiB.
// ---------------------------------------------------------------------------
extern "C" void kernel_launch(void* const* d_in, const int* in_sizes, int n_in,
                              void* d_out, int out_size, void* d_ws, size_t ws_size,
                              hipStream_t stream) {
    const float* x   = (const float*)d_in[0];
    const int*   adj = (const int*)d_in[1];
    const float* Wfc = (const float*)d_in[2];
    const float* bfc = (const float*)d_in[3];
    const float* W1  = (const float*)d_in[4];
    const float* a1s = (const float*)d_in[5];
    const float* a1d = (const float*)d_in[6];
    const float* b1  = (const float*)d_in[7];
    const float* W2  = (const float*)d_in[8];
    const float* a2s = (const float*)d_in[9];
    const float* a2d = (const float*)d_in[10];
    const float* b2  = (const float*)d_in[11];
    float* out = (float*)d_out;

    char* ws = (char*)d_ws;
    size_t off = 0;
    auto alloc = [&](size_t bytes) -> void* {
        void* p = ws + off;
        off += (bytes + 255) & ~(size_t)255;
        return p;
    };
    ushort* xb   = (ushort*)alloc((size_t)N_NODES * 256 * 2);  //  8 MiB
    ushort* h0b  = (ushort*)alloc((size_t)N_NODES * 256 * 2);  //  8 MiB (fc out)
    ushort* h1b  = (ushort*)alloc((size_t)N_NODES * 512 * 2);  // 16 MiB (h1, reused as h2)
    ushort* g1b  = (ushort*)alloc((size_t)N_NODES * 512 * 2);  // 16 MiB (gat1 out)
    int* counts  = (int*)alloc(N_NODES * 4);
    int* offs    = (int*)alloc((N_NODES + 1) * 4);
    int* cursor  = (int*)alloc(N_NODES * 4);
    int* esrc    = (int*)alloc(E_TOT * 4);
    ushort* WfcT = (ushort*)alloc(256 * 256 * 2);
    ushort* W1T  = (ushort*)alloc(512 * 256 * 2);
    ushort* W2T  = (ushort*)alloc(512 * 512 * 2);
    float* als1  = (float*)alloc(N_NODES * 2 * 4);
    float* ald1  = (float*)alloc(N_NODES * 2 * 4);
    float* als2  = (float*)alloc(N_NODES * 4);
    float* ald2  = (float*)alloc(N_NODES * 4);

    // fused prep: cast x, transpose 3 weights, zero counts
    k_prep<<<PREP_TOT / 256, 256, 0, stream>>>(x, xb, Wfc, WfcT, W1, W1T, W2, W2T,
                                               counts);

    // CSR build
    k_hist<<<(E_TOT + 255) / 256, 256, 0, stream>>>(adj, counts);
    k_scan<<<1, 1024, 0, stream>>>(counts, offs, cursor);
    k_scatter<<<(E_TOT + 255) / 256, 256, 0, stream>>>(adj, cursor, esrc);

    // h0 = relu(x @ Wfc + bfc)            [N,256] bf16
    gemm_bt<<<dim3(N_NODES / BM, 256 / BN), 256, 0, stream>>>(xb, WfcT, bfc, h0b,
                                                              N_NODES, 256, 256, 1);
    // h1 = h0 @ W1                        [N,512] bf16
    gemm_bt<<<dim3(N_NODES / BM, 512 / BN), 256, 0, stream>>>(h0b, W1T, nullptr, h1b,
                                                              N_NODES, 512, 256, 0);
    // gat1 attention + aggregation -> relu -> g1b (bf16)
    k_dots<<<N_NODES / 4, 256, 0, stream>>>(h1b, a1s, a1d, als1, ald1, 2);
    k_agg<<<N_NODES / 4, 256, 0, stream>>>(h1b, als1, ald1, offs, esrc, b1,
                                           g1b, nullptr, 2);

    // h2 = g1 @ W2                        [N,512] bf16 (h1b reused; h1 dead)
    gemm_bt<<<dim3(N_NODES / BM, 512 / BN), 256, 0, stream>>>(g1b, W2T, nullptr, h1b,
                                                              N_NODES, 512, 512, 0);
    // gat2 attention + aggregation -> relu -> out (fp32)
    k_dots<<<N_NODES / 4, 256, 0, stream>>>(h1b, a2s, a2d, als2, ald2, 1);
    k_agg<<<N_NODES / 4, 256, 0, stream>>>(h1b, als2, ald2, offs, esrc, b2,
                                           nullptr, out, 1);
}

// Round 8
// 263.082 us; speedup vs baseline: 1.3918x; 1.0232x over previous
//
#include <hip/hip_runtime.h>

// Problem constants (fixed by the reference)
#define N_NODES 16384
#define N_EDGES 262144
#define E_TOT   (N_EDGES + N_NODES)   // edges + self loops = 278528
#define NEG_SLOPE 0.2f

typedef __attribute__((ext_vector_type(8))) short short8;
typedef __attribute__((ext_vector_type(4))) float floatx4;
typedef __attribute__((ext_vector_type(4))) int intx4;

__device__ __forceinline__ float bf2f(ushort u) {
    return __uint_as_float(((unsigned)u) << 16);
}
__device__ __forceinline__ ushort f2bf(float f) {
    unsigned u = __float_as_uint(f);
    u += 0x7fffu + ((u >> 16) & 1u);   // round-to-nearest-even
    return (ushort)(u >> 16);
}
__device__ __forceinline__ float leaky(float x) {
    return x > 0.f ? x : NEG_SLOPE * x;
}

// ---------------------------------------------------------------------------
// Fused prep: x f32->bf16 cast, 3 weight transposes (+bf16), counts zeroing.
// ---------------------------------------------------------------------------
#define PREP_CAST   524288
#define PREP_T0     (PREP_CAST)
#define PREP_T1     (PREP_T0 + 65536)
#define PREP_T2     (PREP_T1 + 131072)
#define PREP_Z      (PREP_T2 + 262144)
#define PREP_TOT    (PREP_Z + 4096)

__global__ __launch_bounds__(256) void k_prep(const float* __restrict__ x,
                                              ushort* __restrict__ xb,
                                              const float* __restrict__ Wfc,
                                              ushort* __restrict__ WfcT,
                                              const float* __restrict__ W1,
                                              ushort* __restrict__ W1T,
                                              const float* __restrict__ W2,
                                              ushort* __restrict__ W2T,
                                              int* __restrict__ counts) {
    int idx = blockIdx.x * 256 + threadIdx.x;
    if (idx < PREP_CAST) {
        floatx4 v0 = *(const floatx4*)(x + (size_t)idx * 8);
        floatx4 v1 = *(const floatx4*)(x + (size_t)idx * 8 + 4);
        short8 r;
        r[0] = (short)f2bf(v0[0]); r[1] = (short)f2bf(v0[1]);
        r[2] = (short)f2bf(v0[2]); r[3] = (short)f2bf(v0[3]);
        r[4] = (short)f2bf(v1[0]); r[5] = (short)f2bf(v1[1]);
        r[6] = (short)f2bf(v1[2]); r[7] = (short)f2bf(v1[3]);
        *(short8*)(xb + (size_t)idx * 8) = r;
    } else if (idx < PREP_T1) {
        int t = idx - PREP_T0;                 // K=256, N=256
        int k = t >> 8, n = t & 255;
        WfcT[n * 256 + k] = f2bf(Wfc[t]);
    } else if (idx < PREP_T2) {
        int t = idx - PREP_T1;                 // K=256, N=512
        int k = t >> 9, n = t & 511;
        W1T[n * 256 + k] = f2bf(W1[t]);
    } else if (idx < PREP_Z) {
        int t = idx - PREP_T2;                 // K=512, N=512
        int k = t >> 9, n = t & 511;
        W2T[n * 512 + k] = f2bf(W2[t]);
    } else if (idx < PREP_TOT) {
        int t = idx - PREP_Z;
        *(intx4*)(counts + t * 4) = (intx4){0, 0, 0, 0};
    }
}

// ---------------------------------------------------------------------------
// CSR build: histogram of dst, shfl-based scan, scatter src indices
// ---------------------------------------------------------------------------
__global__ __launch_bounds__(256) void k_hist(const int* __restrict__ adj,
                                              int* __restrict__ counts) {
    int e = blockIdx.x * 256 + threadIdx.x;
    if (e < E_TOT) {
        int d = (e < N_EDGES) ? adj[N_EDGES + e] : (e - N_EDGES);
        atomicAdd(&counts[d], 1);
    }
}

__global__ __launch_bounds__(1024) void k_scan(const int* __restrict__ counts,
                                               int* __restrict__ offs,
                                               int* __restrict__ cursor) {
    __shared__ int wsum[16];
    int t = threadIdx.x, lane = t & 63, w = t >> 6;
    int local[16];
    int tot = 0;
#pragma unroll
    for (int i = 0; i < 16; i++) {
        local[i] = tot;
        tot += counts[t * 16 + i];
    }
    int incl = tot;   // wave-inclusive scan over thread totals
#pragma unroll
    for (int d = 1; d < 64; d <<= 1) {
        int v = __shfl_up(incl, d, 64);
        if (lane >= d) incl += v;
    }
    if (lane == 63) wsum[w] = incl;
    __syncthreads();
    if (w == 0) {
        int v = (lane < 16) ? wsum[lane] : 0;
#pragma unroll
        for (int d = 1; d < 16; d <<= 1) {
            int u = __shfl_up(v, d, 64);
            if (lane >= d) v += u;
        }
        if (lane < 16) wsum[lane] = v;
    }
    __syncthreads();
    int base = ((w == 0) ? 0 : wsum[w - 1]) + incl - tot;
#pragma unroll
    for (int i = 0; i < 16; i++) {
        int o = base + local[i];
        offs[t * 16 + i] = o;
        cursor[t * 16 + i] = o;
    }
    if (t == 1023) offs[N_NODES] = wsum[15];
}

__global__ __launch_bounds__(256) void k_scatter(const int* __restrict__ adj,
                                                 int* __restrict__ cursor,
                                                 int* __restrict__ esrc) {
    int e = blockIdx.x * 256 + threadIdx.x;
    if (e < E_TOT) {
        int s, d;
        if (e < N_EDGES) { s = adj[e]; d = adj[N_EDGES + e]; }
        else             { s = e - N_EDGES; d = s; }
        int pos = atomicAdd(&cursor[d], 1);
        esrc[pos] = s;
    }
}

// ---------------------------------------------------------------------------
// 128x128-tile GEMM: C[M,Nc] = act(A[M,K] @ B[K,Nc] + bias), bf16 in/out,
// fp32 accumulate. BK=64, 4 waves (2x2 of 64x64), 4x4 MFMA tiles per wave.
// Staging: explicit short8 global loads -> ds_write_b128, padded LDS (LDK2=72).
// mfma_f32_16x16x32_bf16 layouts (HW-verified):
//   A frag: A[m=lane&15][k=(lane>>4)*8 + j]
//   B frag: B[k=(lane>>4)*8 + j][n=lane&15]  (from BT rows)
//   C/D:    col=lane&15, row=(lane>>4)*4 + reg
// ---------------------------------------------------------------------------
#define GM 128
#define GN 128
#define GK 64
#define LDK2 72

__global__ __launch_bounds__(256) void gemm128(const ushort* __restrict__ A,
                                               const ushort* __restrict__ BT,
                                               const float* __restrict__ bias,
                                               ushort* __restrict__ C,
                                               int M, int Nc, int K, int relu) {
    __shared__ ushort As[GM * LDK2];   // 18 KB
    __shared__ ushort Bs[GN * LDK2];   // 18 KB
    int tid = threadIdx.x, wave = tid >> 6, lane = tid & 63;
    int quad = lane >> 4, l16 = lane & 15;
    int bm = blockIdx.x * GM, bn = blockIdx.y * GN;
    int wm = (wave & 1) * 64, wn = (wave >> 1) * 64;

    floatx4 acc[4][4];
#pragma unroll
    for (int mi = 0; mi < 4; mi++)
#pragma unroll
        for (int ni = 0; ni < 4; ni++)
            acc[mi][ni] = (floatx4){0.f, 0.f, 0.f, 0.f};

    // staging map: chunk ci in [0,1024): row = ci>>3, col = (ci&7)*8
    for (int kb = 0; kb < K; kb += GK) {
        short8 av[4], bv[4];
#pragma unroll
        for (int t = 0; t < 4; t++) {
            int ci = tid + 256 * t;
            int row = ci >> 3, col = (ci & 7) * 8;
            av[t] = *(const short8*)(A + (size_t)(bm + row) * K + kb + col);
            bv[t] = *(const short8*)(BT + (size_t)(bn + row) * K + kb + col);
        }
        __syncthreads();   // previous iteration's fragment reads complete
#pragma unroll
        for (int t = 0; t < 4; t++) {
            int ci = tid + 256 * t;
            int row = ci >> 3, col = (ci & 7) * 8;
            *(short8*)&As[row * LDK2 + col] = av[t];
            *(short8*)&Bs[row * LDK2 + col] = bv[t];
        }
        __syncthreads();

#pragma unroll
        for (int kk = 0; kk < GK; kk += 32) {
            short8 af[4], bf[4];
#pragma unroll
            for (int mi = 0; mi < 4; mi++)
                af[mi] = *(const short8*)&As[(wm + mi * 16 + l16) * LDK2 + kk + quad * 8];
#pragma unroll
            for (int ni = 0; ni < 4; ni++)
                bf[ni] = *(const short8*)&Bs[(wn + ni * 16 + l16) * LDK2 + kk + quad * 8];
#pragma unroll
            for (int mi = 0; mi < 4; mi++)
#pragma unroll
                for (int ni = 0; ni < 4; ni++)
                    acc[mi][ni] = __builtin_amdgcn_mfma_f32_16x16x32_bf16(
                        af[mi], bf[ni], acc[mi][ni], 0, 0, 0);
        }
    }

#pragma unroll
    for (int mi = 0; mi < 4; mi++) {
        int row = bm + wm + mi * 16 + quad * 4;
#pragma unroll
        for (int ni = 0; ni < 4; ni++) {
            int col = bn + wn + ni * 16 + l16;
            float bv = bias ? bias[col] : 0.f;
#pragma unroll
            for (int i = 0; i < 4; i++) {
                float v = acc[mi][ni][i] + bv;
                if (relu) v = fmaxf(v, 0.f);
                C[(size_t)(row + i) * Nc + col] = f2bf(v);
            }
        }
    }
}

// ---------------------------------------------------------------------------
// Attention logits: h bf16, a-vectors fp32. One wave per node.
// ---------------------------------------------------------------------------
__global__ __launch_bounds__(256) void k_dots(const ushort* __restrict__ h,
                                              const float* __restrict__ asrc,
                                              const float* __restrict__ adst,
                                              float* __restrict__ als,
                                              float* __restrict__ ald,
                                              int heads) {
    int wave = threadIdx.x >> 6, lane = threadIdx.x & 63;
    int n = blockIdx.x * 4 + wave;
    const ushort* hr = h + (size_t)n * 512;
    int c = lane * 8;
    short8 hv = *(const short8*)(hr + c);
    floatx4 s0 = *(const floatx4*)(asrc + c);
    floatx4 s1 = *(const floatx4*)(asrc + c + 4);
    floatx4 d0 = *(const floatx4*)(adst + c);
    floatx4 d1 = *(const floatx4*)(adst + c + 4);
    float ps = 0.f, pd = 0.f;
#pragma unroll
    for (int j = 0; j < 4; j++) {
        float hf0 = bf2f((ushort)hv[j]);
        float hf1 = bf2f((ushort)hv[j + 4]);
        ps += hf0 * s0[j] + hf1 * s1[j];
        pd += hf0 * d0[j] + hf1 * d1[j];
    }
    int w = (heads == 2) ? 32 : 64;
    for (int m = 1; m < w; m <<= 1) {
        ps += __shfl_xor(ps, m, 64);
        pd += __shfl_xor(pd, m, 64);
    }
    if (heads == 2) {
        if (lane == 0)  { als[n * 2]     = ps; ald[n * 2]     = pd; }
        if (lane == 32) { als[n * 2 + 1] = ps; ald[n * 2 + 1] = pd; }
    } else {
        if (lane == 0)  { als[n] = ps; ald[n] = pd; }
    }
}

// ---------------------------------------------------------------------------
// Segment softmax + aggregation, one wave per node, barrier-free.
// R8 FIX: all __shfl broadcasts execute UNCONDITIONALLY (full exec mask),
// select per-lane afterwards. ds_bpermute data from inactive source lanes
// is undefined — R6/R7 had the shfl inside a myhead-divergent ternary.
// ---------------------------------------------------------------------------
__global__ __launch_bounds__(256) void k_agg(const ushort* __restrict__ h,
                                             const float* __restrict__ als,
                                             const float* __restrict__ ald,
                                             const int* __restrict__ offs,
                                             const int* __restrict__ esrc,
                                             const float* __restrict__ bias,
                                             ushort* __restrict__ outb,
                                             float* __restrict__ outf,
                                             int heads) {
    int wave = threadIdx.x >> 6, lane = threadIdx.x & 63;
    int n = blockIdx.x * 4 + wave;
    int base = offs[n];
    int deg  = offs[n + 1] - base;

    int myhead = (heads == 2) ? (lane >> 5) : 0;
    int c = (heads == 2) ? (myhead * 256 + (lane & 31) * 8) : lane * 8;

    float aldh0 = ald[n * heads];
    float aldh1 = (heads == 2) ? ald[n * heads + 1] : 0.f;

    // pass 1: per-head max
    float m0 = -1e30f, m1 = -1e30f;
    for (int cb = 0; cb < deg; cb += 64) {
        int i = cb + lane;
        if (i < deg) {
            int s = esrc[base + i];
            m0 = fmaxf(m0, leaky(als[s * heads] + aldh0));
            if (heads == 2) m1 = fmaxf(m1, leaky(als[s * 2 + 1] + aldh1));
        }
    }
#pragma unroll
    for (int msk = 1; msk < 64; msk <<= 1) {
        m0 = fmaxf(m0, __shfl_xor(m0, msk, 64));
        m1 = fmaxf(m1, __shfl_xor(m1, msk, 64));
    }

    // pass 2: per-head denom
    float s0 = 0.f, s1 = 0.f;
    for (int cb = 0; cb < deg; cb += 64) {
        int i = cb + lane;
        if (i < deg) {
            int s = esrc[base + i];
            s0 += __expf(leaky(als[s * heads] + aldh0) - m0);
            if (heads == 2) s1 += __expf(leaky(als[s * 2 + 1] + aldh1) - m1);
        }
    }
#pragma unroll
    for (int msk = 1; msk < 64; msk <<= 1) {
        s0 += __shfl_xor(s0, msk, 64);
        s1 += __shfl_xor(s1, msk, 64);
    }
    float inv0 = 1.f / (s0 + 1e-16f);
    float inv1 = 1.f / (s1 + 1e-16f);

    // pass 3: weighted gather-accumulate, 8 channels (16B) per lane per edge
    float acc[8];
#pragma unroll
    for (int q = 0; q < 8; q++) acc[q] = 0.f;
    const ushort* hc = h + c;

    for (int cb = 0; cb < deg; cb += 64) {
        int i = cb + lane;
        int sv = 0;
        float p0 = 0.f, p1 = 0.f;
        if (i < deg) {
            sv = esrc[base + i];
            p0 = __expf(leaky(als[sv * heads] + aldh0) - m0) * inv0;
            if (heads == 2) p1 = __expf(leaky(als[sv * 2 + 1] + aldh1) - m1) * inv1;
        }
        int cnt = min(64, deg - cb);
        int j = 0;
        for (; j + 4 <= cnt; j += 4) {
            int sj0 = __shfl(sv, j, 64);
            int sj1 = __shfl(sv, j + 1, 64);
            int sj2 = __shfl(sv, j + 2, 64);
            int sj3 = __shfl(sv, j + 3, 64);
            float a00 = __shfl(p0, j, 64),     a01 = __shfl(p1, j, 64);
            float a10 = __shfl(p0, j + 1, 64), a11 = __shfl(p1, j + 1, 64);
            float a20 = __shfl(p0, j + 2, 64), a21 = __shfl(p1, j + 2, 64);
            float a30 = __shfl(p0, j + 3, 64), a31 = __shfl(p1, j + 3, 64);
            float al0 = myhead ? a01 : a00;
            float al1 = myhead ? a11 : a10;
            float al2 = myhead ? a21 : a20;
            float al3 = myhead ? a31 : a30;
            short8 h0v = *(const short8*)(hc + (size_t)sj0 * 512);
            short8 h1v = *(const short8*)(hc + (size_t)sj1 * 512);
            short8 h2v = *(const short8*)(hc + (size_t)sj2 * 512);
            short8 h3v = *(const short8*)(hc + (size_t)sj3 * 512);
#pragma unroll
            for (int q = 0; q < 8; q++) {
                acc[q] += al0 * bf2f((ushort)h0v[q]);
                acc[q] += al1 * bf2f((ushort)h1v[q]);
                acc[q] += al2 * bf2f((ushort)h2v[q]);
                acc[q] += al3 * bf2f((ushort)h3v[q]);
            }
        }
        for (; j < cnt; j++) {
            int s = __shfl(sv, j, 64);
            float a0 = __shfl(p0, j, 64), a1 = __shfl(p1, j, 64);
            float al = myhead ? a1 : a0;
            short8 hv = *(const short8*)(hc + (size_t)s * 512);
#pragma unroll
            for (int q = 0; q < 8; q++) acc[q] += al * bf2f((ushort)hv[q]);
        }
    }

    float v[8];
#pragma unroll
    for (int q = 0; q < 8; q++) v[q] = fmaxf(acc[q] + bias[c + q], 0.f);
    if (outf) {
        float* op = outf + (size_t)n * 512 + c;
        *(floatx4*)op       = (floatx4){v[0], v[1], v[2], v[3]};
        *(floatx4*)(op + 4) = (floatx4){v[4], v[5], v[6], v[7]};
    } else {
        short8 r;
#pragma unroll
        for (int q = 0; q < 8; q++) r[q] = (short)f2bf(v[q]);
        *(short8*)(outb + (size_t)n * 512 + c) = r;
    }
}

// ---------------------------------------------------------------------------
// R8: fix divergent-shfl bug in k_agg (unconditional broadcasts + select).
// Keeps gemm128 (ds_write staging), shfl scan, x4 unroll. Workspace ~52 MiB.
// ---------------------------------------------------------------------------
extern "C" void kernel_launch(void* const* d_in, const int* in_sizes, int n_in,
                              void* d_out, int out_size, void* d_ws, size_t ws_size,
                              hipStream_t stream) {
    const float* x   = (const float*)d_in[0];
    const int*   adj = (const int*)d_in[1];
    const float* Wfc = (const float*)d_in[2];
    const float* bfc = (const float*)d_in[3];
    const float* W1  = (const float*)d_in[4];
    const float* a1s = (const float*)d_in[5];
    const float* a1d = (const float*)d_in[6];
    const float* b1  = (const float*)d_in[7];
    const float* W2  = (const float*)d_in[8];
    const float* a2s = (const float*)d_in[9];
    const float* a2d = (const float*)d_in[10];
    const float* b2  = (const float*)d_in[11];
    float* out = (float*)d_out;

    char* ws = (char*)d_ws;
    size_t off = 0;
    auto alloc = [&](size_t bytes) -> void* {
        void* p = ws + off;
        off += (bytes + 255) & ~(size_t)255;
        return p;
    };
    ushort* xb   = (ushort*)alloc((size_t)N_NODES * 256 * 2);
    ushort* h0b  = (ushort*)alloc((size_t)N_NODES * 256 * 2);
    ushort* h1b  = (ushort*)alloc((size_t)N_NODES * 512 * 2);
    ushort* g1b  = (ushort*)alloc((size_t)N_NODES * 512 * 2);
    int* counts  = (int*)alloc(N_NODES * 4);
    int* offs    = (int*)alloc((N_NODES + 1) * 4);
    int* cursor  = (int*)alloc(N_NODES * 4);
    int* esrc    = (int*)alloc(E_TOT * 4);
    ushort* WfcT = (ushort*)alloc(256 * 256 * 2);
    ushort* W1T  = (ushort*)alloc(512 * 256 * 2);
    ushort* W2T  = (ushort*)alloc(512 * 512 * 2);
    float* als1  = (float*)alloc(N_NODES * 2 * 4);
    float* ald1  = (float*)alloc(N_NODES * 2 * 4);
    float* als2  = (float*)alloc(N_NODES * 4);
    float* ald2  = (float*)alloc(N_NODES * 4);

    // fused prep: cast x, transpose 3 weights, zero counts
    k_prep<<<PREP_TOT / 256, 256, 0, stream>>>(x, xb, Wfc, WfcT, W1, W1T, W2, W2T,
                                               counts);

    // CSR build
    k_hist<<<(E_TOT + 255) / 256, 256, 0, stream>>>(adj, counts);
    k_scan<<<1, 1024, 0, stream>>>(counts, offs, cursor);
    k_scatter<<<(E_TOT + 255) / 256, 256, 0, stream>>>(adj, cursor, esrc);

    // h0 = relu(x @ Wfc + bfc)            [N,256] bf16
    gemm128<<<dim3(N_NODES / GM, 256 / GN), 256, 0, stream>>>(xb, WfcT, bfc, h0b,
                                                              N_NODES, 256, 256, 1);
    // h1 = h0 @ W1                        [N,512] bf16
    gemm128<<<dim3(N_NODES / GM, 512 / GN), 256, 0, stream>>>(h0b, W1T, nullptr, h1b,
                                                              N_NODES, 512, 256, 0);
    // gat1 attention + aggregation -> relu -> g1b (bf16)
    k_dots<<<N_NODES / 4, 256, 0, stream>>>(h1b, a1s, a1d, als1, ald1, 2);
    k_agg<<<N_NODES / 4, 256, 0, stream>>>(h1b, als1, ald1, offs, esrc, b1,
                                           g1b, nullptr, 2);

    // h2 = g1 @ W2                        [N,512] bf16 (h1b reused; h1 dead)
    gemm128<<<dim3(N_NODES / GM, 512 / GN), 256, 0, stream>>>(g1b, W2T, nullptr, h1b,
                                                              N_NODES, 512, 512, 0);
    // gat2 attention + aggregation -> relu -> out (fp32)
    k_dots<<<N_NODES / 4, 256, 0, stream>>>(h1b, a2s, a2d, als2, ald2, 1);
    k_agg<<<N_NODES / 4, 256, 0, stream>>>(h1b, als2, ald2, offs, esrc, b2,
                                           nullptr, out, 1);
}